// Round 28
// baseline (115.039 us; speedup 1.0000x reference)
//
#include <hip/hip_runtime.h>

#define HID 50
#define TSTEPS 512

typedef _Float16 h2v __attribute__((ext_vector_type(2)));

__device__ __forceinline__ float fdot2(h2v a, h2v b, float c) {
#if __has_builtin(__builtin_amdgcn_fdot2)
    return __builtin_amdgcn_fdot2(a, b, c, false);
#else
    asm("v_dot2_f32_f16 %0, %1, %2, %0" : "+v"(c) : "v"(a), "v"(b));
    return c;
#endif
}
__device__ __forceinline__ h2v bits_to_h2(unsigned u) {
    h2v r; __builtin_memcpy(&r, &u, sizeof(r)); return r;
}

// TWO chains in ONE wave, same-step, straight-line (the last untried
// arrangement of the fixed 2-chains-per-SIMD budget).
// Evidence base: cross-wave interleave fails (R16/R21 wall = 2x chain,
// stagger/SGB neutral); phase-split pipelines fail (R19 compiler waits,
// R25/26 asm hazards); straight-line single-phase bodies get correct
// counted first-use lgkmcnt from the compiler (R16/R21-proven). So: 2
// batches/wave, 1 row/lane, SHARED weights (same W row for both batches --
// no R15 register duplication). Superstep: write hA,hB -> 14 quad reads ->
// A-dots (stall ~115, B reads land underneath) -> B-dots (covered).
// ONE exposed LDS latency per TWO steps: ~380cy vs R16's 508.
// 1024 waves = 1/SIMD exactly; no cross-wave scheduling needed at all.
// fp16 h + v_dot2_f32_f16 (proven: absmax 2^-7 vs threshold 2.56e-2).
__global__ __launch_bounds__(64) __attribute__((amdgpu_waves_per_eu(1, 1)))
void rnn_fused(
    const float* __restrict__ x,      // [B, 512, 1]
    const float* __restrict__ W_ih,   // [50, 1]
    const float* __restrict__ W_hh,   // [50, 50]
    const float* __restrict__ b_ih,   // [50]
    const float* __restrict__ b_hh,   // [50]
    const float* __restrict__ W_fc,   // [1, 50]
    const float* __restrict__ b_fc,   // [1]
    float* __restrict__ out)          // [B, 1]
{
    const int j  = threadIdx.x;       // 0..63; lanes 50..63 only stage x
    const int bA = blockIdx.x * 2;
    const int bB = bA + 1;
    const int jj = (j < HID) ? j : 0;
    const float SC = 2.8853900817779268f;   // 2*log2(e)

    // ht[0..63] = batch A table, ht[64..127] = batch B table (quads 8..14)
    __shared__ __align__(16) _Float16 ht[128];
    __shared__ __align__(16) float xbufA[64];
    __shared__ __align__(16) float xbufB[64];

    h2v w2[25];                       // row jj weights, shared by A and B
#pragma unroll
    for (int m = 0; m < 25; ++m) {
        h2v t;
        t.x = (_Float16)(W_hh[jj * HID + 2 * m]     * SC);
        t.y = (_Float16)(W_hh[jj * HID + 2 * m + 1] * SC);
        w2[m] = t;
    }
    const float wih  = W_ih[jj] * SC;
    const float btot = (b_ih[jj] + b_hh[jj]) * SC;
    const float wfc  = (j < HID) ? W_fc[jj] : 0.0f;
    const float bfc  = b_fc[0];

    const float* xpA = x + (size_t)bA * TSTEPS;
    const float* xpB = x + (size_t)bB * TSTEPS;
    float xvA = xpA[j], xvB = xpB[j];
    float hnA = 0.0f, hnB = 0.0f;

    ht[j]      = (_Float16)0.0f;      // h0 = 0; slots 50..63 stay 0 forever
    ht[64 + j] = (_Float16)0.0f;

#define DOTS(res, q0, q1, q2, q3, q4, q5, q6, xt)                       \
    {                                                                    \
        float a0 = btot, a1 = 0.f, a2 = 0.f, a3 = 0.f;                   \
        a0 = fdot2(bits_to_h2(q0.x), w2[0],  a0);                        \
        a1 = fdot2(bits_to_h2(q0.y), w2[1],  a1);                        \
        a2 = fdot2(bits_to_h2(q0.z), w2[2],  a2);                        \
        a3 = fdot2(bits_to_h2(q0.w), w2[3],  a3);                        \
        a0 = fdot2(bits_to_h2(q1.x), w2[4],  a0);                        \
        a1 = fdot2(bits_to_h2(q1.y), w2[5],  a1);                        \
        a2 = fdot2(bits_to_h2(q1.z), w2[6],  a2);                        \
        a3 = fdot2(bits_to_h2(q1.w), w2[7],  a3);                        \
        a0 = fdot2(bits_to_h2(q2.x), w2[8],  a0);                        \
        a1 = fdot2(bits_to_h2(q2.y), w2[9],  a1);                        \
        a2 = fdot2(bits_to_h2(q2.z), w2[10], a2);                        \
        a3 = fdot2(bits_to_h2(q2.w), w2[11], a3);                        \
        a0 = fdot2(bits_to_h2(q3.x), w2[12], a0);                        \
        a1 = fdot2(bits_to_h2(q3.y), w2[13], a1);                        \
        a2 = fdot2(bits_to_h2(q3.z), w2[14], a2);                        \
        a3 = fdot2(bits_to_h2(q3.w), w2[15], a3);                        \
        a0 = fdot2(bits_to_h2(q4.x), w2[16], a0);                        \
        a1 = fdot2(bits_to_h2(q4.y), w2[17], a1);                        \
        a2 = fdot2(bits_to_h2(q4.z), w2[18], a2);                        \
        a3 = fdot2(bits_to_h2(q4.w), w2[19], a3);                        \
        a0 = fdot2(bits_to_h2(q5.x), w2[20], a0);                        \
        a1 = fdot2(bits_to_h2(q5.y), w2[21], a1);                        \
        a2 = fdot2(bits_to_h2(q5.z), w2[22], a2);                        \
        a3 = fdot2(bits_to_h2(q5.w), w2[23], a3);                        \
        a0 = fdot2(bits_to_h2(q6.x), w2[24], a0);                        \
        const float z = fmaf(xt, wih, (a0 + a1) + (a2 + a3));            \
        const float e = __builtin_amdgcn_exp2f(z);                       \
        res = fmaf(-2.0f, __builtin_amdgcn_rcpf(e + 1.0f), 1.0f);        \
    }

    for (int c = 0; c < TSTEPS / 64; ++c) {
        xbufA[j] = xvA;               // staged by all 64 lanes, in-order DS
        xbufB[j] = xvB;
        float xnA = 0.0f, xnB = 0.0f;
        if (c + 1 < TSTEPS / 64) {
            xnA = xpA[(c + 1) * 64 + j];
            xnB = xpB[(c + 1) * 64 + j];
        }

        if (j < HID) {                // one exec-mask toggle per 64 steps
            for (int g = 0; g < 8; ++g) {
#pragma unroll
                for (int ii = 0; ii < 8; ++ii) {
                    const int t = g * 8 + ii;

                    // publish both h's (in-order DS: queues ahead of reads)
                    ht[j]      = (_Float16)hnA;
                    ht[64 + j] = (_Float16)hnB;
                    const float xtA = xbufA[t];
                    const float xtB = xbufB[t];

                    const uint4* h8 = reinterpret_cast<const uint4*>(ht);
                    uint4 a0q = h8[0], a1q = h8[1], a2q = h8[2], a3q = h8[3],
                          a4q = h8[4], a5q = h8[5], a6q = h8[6];
                    uint4 b0q = h8[8], b1q = h8[9], b2q = h8[10], b3q = h8[11],
                          b4q = h8[12], b5q = h8[13], b6q = h8[14];

                    // A-dots first (first-use wait leaves B's reads in
                    // flight -- counted lgkmcnt, R16-proven mechanism);
                    // B's reads land under A's ~115cy of compute.
                    DOTS(hnA, a0q, a1q, a2q, a3q, a4q, a5q, a6q, xtA);
                    DOTS(hnB, b0q, b1q, b2q, b3q, b4q, b5q, b6q, xtB);
                }
            }
        }
        xvA = xnA;
        xvB = xnB;
    }

    // out[b] = sum_j h_T[j]*W_fc[j] + b_fc for both batches
    float pA = hnA * wfc, pB = hnB * wfc;
#pragma unroll
    for (int off = 32; off >= 1; off >>= 1) {
        pA += __shfl_xor(pA, off);
        pB += __shfl_xor(pB, off);
    }
    if (j == 0) {
        out[bA] = pA + bfc;
        out[bB] = pB + bfc;
    }
}

extern "C" void kernel_launch(void* const* d_in, const int* in_sizes, int n_in,
                              void* d_out, int out_size, void* d_ws, size_t ws_size,
                              hipStream_t stream) {
    (void)d_ws; (void)ws_size; (void)n_in; (void)out_size;
    const float* x    = (const float*)d_in[0];
    const float* W_ih = (const float*)d_in[1];
    const float* W_hh = (const float*)d_in[2];
    const float* b_ih = (const float*)d_in[3];
    const float* b_hh = (const float*)d_in[4];
    const float* W_fc = (const float*)d_in[5];
    const float* b_fc = (const float*)d_in[6];
    float* out = (float*)d_out;

    const int B = in_sizes[0] / TSTEPS;   // 2048
    rnn_fused<<<dim3(B / 2), dim3(64), 0, stream>>>(x, W_ih, W_hh, b_ih, b_hh,
                                                    W_fc, b_fc, out);
}

// Round 29
// 99.639 us; speedup vs baseline: 1.1546x; 1.1546x over previous
//
#include <hip/hip_runtime.h>

#define HID 50
#define TSTEPS 512

typedef _Float16 h2v __attribute__((ext_vector_type(2)));

__device__ __forceinline__ float fdot2(h2v a, h2v b, float c) {
#if __has_builtin(__builtin_amdgcn_fdot2)
    return __builtin_amdgcn_fdot2(a, b, c, false);
#else
    asm("v_dot2_f32_f16 %0, %1, %2, %0" : "+v"(c) : "v"(a), "v"(b));
    return c;
#endif
}
__device__ __forceinline__ h2v bits_to_h2(unsigned u) {
    h2v r; __builtin_memcpy(&r, &u, sizeof(r)); return r;
}

// FINAL: session-best structure (R22, re-measured R27: 99.7us bench /
// 108.3us rocprof steady-state).
// 1 batch/wave, fp16 h table in LDS, broadcast = 7x ds_read_b128 same-addr
// (conflict-free), dot = 25 v_dot2_f32_f16 (fp32 accum), barrier-free
// (same-wave in-order DS, proven R18/R19), 50-lane predication, s_setprio
// phase split (mem-issue @0, compute @1: +4%, the only scheduling lever
// that measured real out of barriers/traffic/stagger/SGB/asm-waits).
//
// Structural ceiling (13 structures measured): 512 serial steps x 50-wide
// all-to-all; wave = broadcast domain => 2048 waves = 2/SIMD fixed.
// Wall 508cy/step-pair = 2x165 issue + ~180cy un-hideable LDS round-trip.
// Issue floor 330cy/pair ~= 70us unreachable: cross-wave convoy (R16/R21),
// phase-split killed by compiler waits (R19), asm counted waits corrupt
// (R25/26), in-wave 2-chain issue-bloats (R28). Alternatives dead: MFMA
// occupancy-starved (R12: 357us), readlane SGPR-hazard (R10), pk half-rate
// (R5), row-split doubles issue (R20), 2-row/lane overshoots (R15).
__global__ __launch_bounds__(64) __attribute__((amdgpu_waves_per_eu(2, 2)))
void rnn_fused(
    const float* __restrict__ x,      // [B, 512, 1]
    const float* __restrict__ W_ih,   // [50, 1]
    const float* __restrict__ W_hh,   // [50, 50]
    const float* __restrict__ b_ih,   // [50]
    const float* __restrict__ b_hh,   // [50]
    const float* __restrict__ W_fc,   // [1, 50]
    const float* __restrict__ b_fc,   // [1]
    float* __restrict__ out)          // [B, 1]
{
    const int b = blockIdx.x;
    const int j = threadIdx.x;        // 0..63; lanes 50..63 only stage x
    __shared__ __align__(16) _Float16 hht[64];   // h table; slots 50..63 = 0
    __shared__ __align__(16) float xbuf[64];

    const int jj = (j < HID) ? j : 0;
    const float SC = 2.8853900817779268f;   // 2*log2(e)

    h2v w2[25];
#pragma unroll
    for (int m = 0; m < 25; ++m) {
        h2v t;
        t.x = (_Float16)(W_hh[jj * HID + 2 * m]     * SC);
        t.y = (_Float16)(W_hh[jj * HID + 2 * m + 1] * SC);
        w2[m] = t;
    }
    const float wih  = W_ih[jj] * SC;
    const float btot = (b_ih[jj] + b_hh[jj]) * SC;
    const float wfc  = (j < HID) ? W_fc[jj] : 0.0f;
    const float bfc  = b_fc[0];

    const float* xb = x + (size_t)b * TSTEPS;
    float xv = xb[j];                 // 64 timesteps of x, one per lane
    float hn = 0.0f;
    hht[j] = (_Float16)0.0f;          // h0 = 0 (slots 50..63 stay 0 forever)
    // no barrier: same-wave in-order DS covers write->read (R18/R19-proven)

    for (int c = 0; c < TSTEPS / 64; ++c) {
        xbuf[j] = xv;                 // staged by all 64 lanes, in-order DS
        float xv_next = 0.0f;
        if (c + 1 < TSTEPS / 64) xv_next = xb[(c + 1) * 64 + j];

        if (j < HID) {                // one exec-mask toggle per 64 steps
            for (int g = 0; g < 8; ++g) {
#pragma unroll
                for (int ii = 0; ii < 8; ++ii) {
                    const int t = g * 8 + ii;

                    // ---- memory-issue phase at prio 0
                    __builtin_amdgcn_s_setprio(0);
                    hht[j] = (_Float16)hn;        // write first: queues ahead
                    const float xt = xbuf[t];     // of the reads below
                    const uint4* h8 = reinterpret_cast<const uint4*>(hht);
                    uint4 u0 = h8[0], u1 = h8[1], u2 = h8[2], u3 = h8[3],
                          u4 = h8[4], u5 = h8[5], u6 = h8[6];

                    // ---- compute phase at prio 1
                    __builtin_amdgcn_s_setprio(1);
                    float a0 = btot, a1 = 0.f, a2 = 0.f, a3 = 0.f;
                    a0 = fdot2(bits_to_h2(u0.x), w2[0],  a0);
                    a1 = fdot2(bits_to_h2(u0.y), w2[1],  a1);
                    a2 = fdot2(bits_to_h2(u0.z), w2[2],  a2);
                    a3 = fdot2(bits_to_h2(u0.w), w2[3],  a3);
                    a0 = fdot2(bits_to_h2(u1.x), w2[4],  a0);
                    a1 = fdot2(bits_to_h2(u1.y), w2[5],  a1);
                    a2 = fdot2(bits_to_h2(u1.z), w2[6],  a2);
                    a3 = fdot2(bits_to_h2(u1.w), w2[7],  a3);
                    a0 = fdot2(bits_to_h2(u2.x), w2[8],  a0);
                    a1 = fdot2(bits_to_h2(u2.y), w2[9],  a1);
                    a2 = fdot2(bits_to_h2(u2.z), w2[10], a2);
                    a3 = fdot2(bits_to_h2(u2.w), w2[11], a3);
                    a0 = fdot2(bits_to_h2(u3.x), w2[12], a0);
                    a1 = fdot2(bits_to_h2(u3.y), w2[13], a1);
                    a2 = fdot2(bits_to_h2(u3.z), w2[14], a2);
                    a3 = fdot2(bits_to_h2(u3.w), w2[15], a3);
                    a0 = fdot2(bits_to_h2(u4.x), w2[16], a0);
                    a1 = fdot2(bits_to_h2(u4.y), w2[17], a1);
                    a2 = fdot2(bits_to_h2(u4.z), w2[18], a2);
                    a3 = fdot2(bits_to_h2(u4.w), w2[19], a3);
                    a0 = fdot2(bits_to_h2(u5.x), w2[20], a0);
                    a1 = fdot2(bits_to_h2(u5.y), w2[21], a1);
                    a2 = fdot2(bits_to_h2(u5.z), w2[22], a2);
                    a3 = fdot2(bits_to_h2(u5.w), w2[23], a3);
                    a0 = fdot2(bits_to_h2(u6.x), w2[24], a0);
                    const float z = fmaf(xt, wih, (a0 + a1) + (a2 + a3));

                    // tanh(s) = 1 - 2/(exp2(z)+1); saturates at +-inf
                    const float e = __builtin_amdgcn_exp2f(z);
                    const float r = __builtin_amdgcn_rcpf(e + 1.0f);
                    hn = fmaf(-2.0f, r, 1.0f);

                    __builtin_amdgcn_sched_barrier(0);  // pin step boundary
                }
            }
        }
        xv = xv_next;
    }
    __builtin_amdgcn_s_setprio(0);

    // out[b] = sum_j h_T[j]*W_fc[j] + b_fc (lanes >= 50: hn=0, wfc=0)
    float pr = hn * wfc;
#pragma unroll
    for (int off = 32; off >= 1; off >>= 1) pr += __shfl_xor(pr, off);
    if (j == 0) out[b] = pr + bfc;
}

extern "C" void kernel_launch(void* const* d_in, const int* in_sizes, int n_in,
                              void* d_out, int out_size, void* d_ws, size_t ws_size,
                              hipStream_t stream) {
    (void)d_ws; (void)ws_size; (void)n_in; (void)out_size;
    const float* x    = (const float*)d_in[0];
    const float* W_ih = (const float*)d_in[1];
    const float* W_hh = (const float*)d_in[2];
    const float* b_ih = (const float*)d_in[3];
    const float* b_hh = (const float*)d_in[4];
    const float* W_fc = (const float*)d_in[5];
    const float* b_fc = (const float*)d_in[6];
    float* out = (float*)d_out;

    const int B = in_sizes[0] / TSTEPS;   // 2048
    rnn_fused<<<dim3(B), dim3(64), 0, stream>>>(x, W_ih, W_hh, b_ih, b_hh,
                                                W_fc, b_fc, out);
}